// Round 6
// baseline (653.211 us; speedup 1.0000x reference)
//
#include <hip/hip_runtime.h>
#include <hip/hip_bf16.h>

// Problem dims
#define NNODE 32
#define NB    64
#define NDIM  32
#define NSTEP 8
#define NE    992
#define NTT   16

typedef __bf16 bf16;
typedef __attribute__((ext_vector_type(8))) __bf16 bf16x8;
typedef __attribute__((ext_vector_type(4))) __bf16 bf16x4;
typedef __attribute__((ext_vector_type(4))) float  f32x4;

__device__ __forceinline__ f32x4 mfma_bf16(bf16x8 a, bf16x8 b, f32x4 c) {
  return __builtin_amdgcn_mfma_f32_16x16x32_bf16(a, b, c, 0, 0, 0);
}
__device__ __forceinline__ float sigm(float x) { return 1.0f / (1.0f + __expf(-x)); }
__device__ __forceinline__ float tanh_f(float x) {
  x = fminf(fmaxf(x, -15.0f), 15.0f);
  float e = __expf(2.0f * x);
  return (e - 1.0f) / (e + 1.0f);
}

// ---------------------------------------------------------------------------
// Swizzle all weights into MFMA B-fragment bf16 order (round-3 validated).
// ---------------------------------------------------------------------------
__global__ void prep_weights(
    const float* __restrict__ msgW1, const float* __restrict__ msgW2,
    const float* __restrict__ geWi,  const float* __restrict__ geWh,
    const float* __restrict__ gnWi,  const float* __restrict__ gnWh,
    const float* __restrict__ oW1,   const float* __restrict__ oW2,
    const float* __restrict__ oW3,
    bf16* __restrict__ B1, bf16* __restrict__ B2,
    bf16* __restrict__ GI, bf16* __restrict__ GH,
    bf16* __restrict__ GN,
    bf16* __restrict__ OW1s, bf16* __restrict__ OW2s, bf16* __restrict__ OW3s) {
  int u = blockIdx.x * 256 + threadIdx.x;
  if (u < 12288) {
    int k = u >> 12, i = (u >> 6) & 63, h = u & 63;
    int kf = i >> 5, quad = (i >> 3) & 3, j = i & 7;
    int nn = k * 64 + h, nt = nn >> 4, lane = quad * 16 + (nn & 15);
    int slot = ((nt * 2 + kf) * 64 + lane) * 8 + j;
    B1[slot] = (bf16)msgW1[u];
    GI[slot] = (bf16)geWi[u];
    GH[slot] = (bf16)geWh[u];
    int ntl = h >> 4, lane2 = quad * 16 + (h & 15);
    int slot2 = k * 4096 + ((ntl * 2 + kf) * 64 + lane2) * 8 + j;
    B2[slot2] = (bf16)msgW2[u];
  } else if (u < 39936) {
    int v = u - 12288;
    int kk = v / 9216, rem = v % 9216, i = rem / 96, h = rem % 96;
    int kf = i >> 5, loc = i & 31, quad = loc >> 3, j = loc & 7;
    int nn = kk * 96 + h, nt = nn >> 4, lane = quad * 16 + (nn & 15);
    int slot = ((nt * 3 + kf) * 64 + lane) * 8 + j;
    GN[slot]         = (bf16)gnWi[v];
    GN[27648 + slot] = (bf16)gnWh[v];
  } else if (u < 46080) {
    int v = u - 39936; int i = v >> 6, h = v & 63;
    int kf = i >> 5, loc = i & 31, quad = loc >> 3, j = loc & 7;
    int nt = h >> 4, lane = quad * 16 + (h & 15);
    OW1s[((nt * 3 + kf) * 64 + lane) * 8 + j] = (bf16)oW1[v];
  } else if (u < 50176) {
    int v = u - 46080; int i = v >> 6, h = v & 63;
    int kf = i >> 5, quad = (i >> 3) & 3, j = i & 7;
    int nt = h >> 4, lane = quad * 16 + (h & 15);
    OW2s[((nt * 2 + kf) * 64 + lane) * 8 + j] = (bf16)oW2[v];
  } else if (u < 52224) {
    int v = u - 50176; int i = v >> 5, h = v & 31;
    int kf = i >> 5, quad = (i >> 3) & 3, j = i & 7;
    int nt = h >> 4, lane = quad * 16 + (h & 15);
    OW3s[((nt * 2 + kf) * 64 + lane) * 8 + j] = (bf16)oW3[v];
  }
}

// Initial input (t=0) into xf (fp32) + xb (bf16), layout [n][b][d].
__global__ void copy_x(const float* __restrict__ x, float* __restrict__ xf,
                       bf16* __restrict__ xb) {
  int u = blockIdx.x * 256 + threadIdx.x;  // 65536
  int n = u >> 11, b = (u >> 5) & 63, d = u & 31;
  float v = x[((b * 32 + n) * 32 + d) * 8 + 0];
  xf[u] = v;
  xb[u] = (bf16)v;
}

// ---------------------------------------------------------------------------
// One-time PQ for t=0: P[n] = x[n] @ W1_top + b1  (cols 0..191),
//                      Q[n] = x[n] @ W1_bot        (cols 192..383).
// B1 fragment (nt,kf): kf=0 -> W1 rows 0..31 (top), kf=1 -> rows 32..63 (bot).
// ---------------------------------------------------------------------------
__global__ __launch_bounds__(256) void pq_init(
    const bf16* __restrict__ xb, const bf16* __restrict__ B1,
    const float* __restrict__ mb1, bf16* __restrict__ PQ) {
  int n = blockIdx.x, tid = threadIdx.x;
  int wv = tid >> 6, ln = tid & 63, quad = ln >> 4, l16 = ln & 15;
  bf16x8 xfrag = *(const bf16x8*)(xb + n * 2048 + (wv * 16 + l16) * 32 + quad * 8);
  bf16* pqbase = PQ + ((size_t)(n * 64 + wv * 16)) * 384;
#pragma unroll
  for (int c2 = 0; c2 < 24; c2++) {
    int nt = c2 >> 1, kf = c2 & 1;
    bf16x8 bfrag = *(const bf16x8*)&B1[(nt * 2 + kf) * 512 + ln * 8];
    f32x4 acc = {0.f, 0.f, 0.f, 0.f};
    acc = mfma_bf16(xfrag, bfrag, acc);
    int col = nt * 16 + l16;
    float badd = kf ? 0.f : mb1[col];
#pragma unroll
    for (int rr = 0; rr < 4; rr++)
      pqbase[(quad * 4 + rr) * 384 + kf * 192 + col] = (bf16)(acc[rr] + badd);
  }
}

// ---------------------------------------------------------------------------
// Edge step v6: layer-1 factored out (P/Q precomputed per node). Phase 1 is a
// pure streaming h1 = relu(P[row]+Q[col]) into LDS (no MFMA, no x staging, b1
// already folded into P). Then L2 + z-mix + GRU as in the round-1 v4 kernel.
// 2 edges/block, 8 waves = (rg 0..3) x (cg 0..1). 3 barriers total (was 6).
// ---------------------------------------------------------------------------
__global__ __launch_bounds__(512, 4) void edge_step(
    const bf16* __restrict__ PQ, const int* __restrict__ es,
    const float* __restrict__ z,
    const bf16* __restrict__ B2,
    const float* __restrict__ mb2,
    const bf16* __restrict__ GI, const bf16* __restrict__ GH,
    const float* __restrict__ gbi, const float* __restrict__ gbh,
    bf16* __restrict__ hed, int t) {
  __shared__ __align__(16) char scrbuf[51200];
  __shared__ float zL[2][64][3];
  __shared__ float biasL[576];  // mb2 | gbi | gbh (192 each)
  bf16 (*A)[64][72]   = (bf16(*)[64][72])scrbuf;    // mix / state
  bf16 (*A2)[64][200] = (bf16(*)[64][200])scrbuf;   // h1 (aliases A)

  int e0 = blockIdx.x * 2, tid = threadIdx.x;
  int c0_ = es[e0],     r0 = es[NE + e0];
  int c1_ = es[e0 + 1], r1 = es[NE + e0 + 1];
  for (int u = tid; u < 576; u += 512)
    biasL[u] = (u < 192) ? mb2[u] : (u < 384) ? gbi[u - 192] : gbh[u - 384];
  for (int u = tid; u < 384; u += 512) {
    int pe = u / 192, rem = u % 192, b = rem / 3, k = rem % 3;
    zL[pe][b][k] = z[(b * NE + e0 + pe) * 3 + k];
  }
  // ---- phase 1: h1 = relu(P[row] + Q[col]) streamed into A2 ----
  for (int u = tid; u < 3072; u += 512) {
    int pe = u / 1536, rem = u - pe * 1536;   // 1536 = 64 rows * 24 chunks
    int b = rem / 24, c8 = rem - b * 24;
    int nrow = pe ? r1 : r0, ncol = pe ? c1_ : c0_;
    bf16x8 pv = *(const bf16x8*)&PQ[((size_t)(nrow * 64 + b)) * 384 + c8 * 8];
    bf16x8 qv = *(const bf16x8*)&PQ[((size_t)(ncol * 64 + b)) * 384 + 192 + c8 * 8];
    bf16x8 hv;
#pragma unroll
    for (int j2 = 0; j2 < 8; j2++) {
      float s = (float)pv[j2] + (float)qv[j2];
      hv[j2] = (bf16)(s > 0.f ? s : 0.f);
    }
    *(bf16x8*)&A2[pe][b][c8 * 8] = hv;
  }
  __syncthreads();
  int wv = tid >> 6, ln = tid & 63, quad = ln >> 4, l16 = ln & 15;
  int rg = wv & 3, cg = wv >> 2;       // row-group 0..3, col-group 0..1
  int m = rg * 16 + l16;
  // ---- layer 2: per-type [64x64] blocks; this wave does out-tiles {2cg,2cg+1} ----
  f32x4 acc2[2][3][2];  // [pe][kt][oi]
#pragma unroll
  for (int pe = 0; pe < 2; pe++)
#pragma unroll
    for (int kt = 0; kt < 3; kt++)
#pragma unroll
      for (int oi = 0; oi < 2; oi++) { f32x4 zz = {0.f,0.f,0.f,0.f}; acc2[pe][kt][oi] = zz; }
#pragma unroll
  for (int kt = 0; kt < 3; kt++) {
    bf16x8 a2f[2][2];
#pragma unroll
    for (int pe = 0; pe < 2; pe++)
#pragma unroll
      for (int kf = 0; kf < 2; kf++)
        a2f[pe][kf] = *(const bf16x8*)&A2[pe][m][kt * 64 + kf * 32 + quad * 8];
#pragma unroll
    for (int oi = 0; oi < 2; oi++) {
      int ot = cg * 2 + oi;
      bf16x8 w0 = *(const bf16x8*)&B2[kt * 4096 + (ot * 2 + 0) * 512 + ln * 8];
      bf16x8 w1 = *(const bf16x8*)&B2[kt * 4096 + (ot * 2 + 1) * 512 + ln * 8];
#pragma unroll
      for (int pe = 0; pe < 2; pe++) {
        acc2[pe][kt][oi] = mfma_bf16(a2f[pe][0], w0, acc2[pe][kt][oi]);
        acc2[pe][kt][oi] = mfma_bf16(a2f[pe][1], w1, acc2[pe][kt][oi]);
      }
    }
  }
  __syncthreads();  // A2 dead -> A (mix/state) may overwrite
  // ---- mix with z, /K -> write into A (own rows x own cols) ----
#pragma unroll
  for (int pe = 0; pe < 2; pe++)
#pragma unroll
    for (int r = 0; r < 4; r++) {
      int b = rg * 16 + quad * 4 + r;
      float z0 = zL[pe][b][0], z1 = zL[pe][b][1], z2 = zL[pe][b][2];
#pragma unroll
      for (int oi = 0; oi < 2; oi++) {
        int o = (cg * 2 + oi) * 16 + l16;
        float h0 = acc2[pe][0][oi][r] + biasL[o];       h0 = h0 > 0.f ? h0 : 0.f;
        float h1 = acc2[pe][1][oi][r] + biasL[64 + o];  h1 = h1 > 0.f ? h1 : 0.f;
        float h2 = acc2[pe][2][oi][r] + biasL[128 + o]; h2 = h2 > 0.f ? h2 : 0.f;
        A[pe][b][o] = (bf16)((h0 * z0 + h1 * z1 + h2 * z2) * (1.0f / 3.0f));
      }
    }
  if (t > 0) {
    __syncthreads();
    // ---- edge GRU: mix (LDS A) + old state (global hed) ----
    bf16x8 ai[2][2], ah[2][2];
#pragma unroll
    for (int pe = 0; pe < 2; pe++) {
      const bf16* hrow = hed + (e0 + pe) * 4096 + m * 64;
#pragma unroll
      for (int kf = 0; kf < 2; kf++) {
        ai[pe][kf] = *(const bf16x8*)&A[pe][m][kf * 32 + quad * 8];
        ah[pe][kf] = *(const bf16x8*)(hrow + kf * 32 + quad * 8);
      }
    }
    // process one 16-wide gate-tile at a time (keeps live accs at 8 f32x4)
#pragma unroll
    for (int oi = 0; oi < 2; oi++) {
      int ot = cg * 2 + oi;
      f32x4 gr[2], gi2[2], gni2[2], gnh2[2];
#pragma unroll
      for (int pe = 0; pe < 2; pe++) {
        f32x4 zz = {0.f,0.f,0.f,0.f};
        gr[pe] = zz; gi2[pe] = zz; gni2[pe] = zz; gnh2[pe] = zz;
      }
#pragma unroll
      for (int g = 0; g < 2; g++) {     // g=0: r-gate (nt=ot), g=1: i-gate (nt=4+ot)
        int nt = g * 4 + ot;
        bf16x8 wi0 = *(const bf16x8*)&GI[(nt * 2 + 0) * 512 + ln * 8];
        bf16x8 wi1 = *(const bf16x8*)&GI[(nt * 2 + 1) * 512 + ln * 8];
        bf16x8 wh0 = *(const bf16x8*)&GH[(nt * 2 + 0) * 512 + ln * 8];
        bf16x8 wh1 = *(const bf16x8*)&GH[(nt * 2 + 1) * 512 + ln * 8];
#pragma unroll
        for (int pe = 0; pe < 2; pe++) {
          f32x4 a = g ? gi2[pe] : gr[pe];
          a = mfma_bf16(ai[pe][0], wi0, a);
          a = mfma_bf16(ai[pe][1], wi1, a);
          a = mfma_bf16(ah[pe][0], wh0, a);
          a = mfma_bf16(ah[pe][1], wh1, a);
          if (g) gi2[pe] = a; else gr[pe] = a;
        }
      }
      {                                  // n-gate (nt=8+ot): i-part and h-part kept apart
        int nt = 8 + ot;
        bf16x8 wi0 = *(const bf16x8*)&GI[(nt * 2 + 0) * 512 + ln * 8];
        bf16x8 wi1 = *(const bf16x8*)&GI[(nt * 2 + 1) * 512 + ln * 8];
        bf16x8 wh0 = *(const bf16x8*)&GH[(nt * 2 + 0) * 512 + ln * 8];
        bf16x8 wh1 = *(const bf16x8*)&GH[(nt * 2 + 1) * 512 + ln * 8];
#pragma unroll
        for (int pe = 0; pe < 2; pe++) {
          gni2[pe] = mfma_bf16(ai[pe][0], wi0, gni2[pe]);
          gni2[pe] = mfma_bf16(ai[pe][1], wi1, gni2[pe]);
          gnh2[pe] = mfma_bf16(ah[pe][0], wh0, gnh2[pe]);
          gnh2[pe] = mfma_bf16(ah[pe][1], wh1, gnh2[pe]);
        }
      }
#pragma unroll
      for (int pe = 0; pe < 2; pe++)
#pragma unroll
        for (int r = 0; r < 4; r++) {
          int b = rg * 16 + quad * 4 + r;
          int o = ot * 16 + l16;
          float xr = gr[pe][r]   + biasL[192 + o]       + biasL[384 + o];
          float xi = gi2[pe][r]  + biasL[256 + o]       + biasL[448 + o];
          float xn = gni2[pe][r] + biasL[320 + o];
          float hn = gnh2[pe][r] + biasL[512 + o];
          float rgt = sigm(xr);
          float ig  = sigm(xi);
          float ng  = tanh_f(xn + rgt * hn);
          float hv  = (float)hed[(e0 + pe) * 4096 + b * 64 + o];
          A[pe][b][o] = (bf16)((1.0f - ig) * ng + ig * hv);
        }
    }
  }
  __syncthreads();
  // coalesced writeback of new state
  for (int u = tid; u < 1024; u += 512) {
    int pe = u >> 9, c = u & 511;
    int b = c >> 3, j = c & 7;
    *(bf16x8*)(hed + (e0 + pe) * 4096 + b * 64 + j * 8) = *(const bf16x8*)&A[pe][b][j * 8];
  }
}

// ---------------------------------------------------------------------------
// Node kernel (round-1 256-thr version + fused PQ epilogue): scatter-mean agg
// + node GRU (MFMA) + 3-layer out-MLP + next-step P/Q for this (n, quarter).
// ---------------------------------------------------------------------------
__global__ __launch_bounds__(256) void node_kernel(
    const float* __restrict__ x, const bf16* __restrict__ hed,
    float* __restrict__ xf, float* __restrict__ hnode,
    const bf16* __restrict__ GN,
    const float* __restrict__ gnbi, const float* __restrict__ gnbh,
    const bf16* __restrict__ OW1, const float* __restrict__ ob1,
    const bf16* __restrict__ OW2, const float* __restrict__ ob2,
    const bf16* __restrict__ OW3, const float* __restrict__ ob3,
    const bf16* __restrict__ B1, const float* __restrict__ mb1,
    bf16* __restrict__ PQ,
    float* __restrict__ out, int t) {
  __shared__ float aggf[16][64];
  __shared__ float xinf[16][32];
  __shared__ float hvf[16][96];
  __shared__ __align__(16) bf16 c0b[16][112];
  __shared__ __align__(16) bf16 hvb[16][112];
  __shared__ float gsum[2][16][290];
  __shared__ __align__(16) bf16 cnb[16][112];
  __shared__ __align__(16) bf16 s1b[16][112];
  __shared__ __align__(16) bf16 s2b[16][112];
  __shared__ __align__(16) bf16 xnb[16][40];   // x_next, padded (80B rows)
  int nq = blockIdx.x, n = nq >> 2, q = nq & 3;
  int tid = threadIdx.x;
  {
    int r = tid >> 4, o4 = tid & 15;
    const bf16x4* bp = (const bf16x4*)hed + (size_t)n * 31 * 1024 + (q * 16 + r) * 16 + o4;
    float sx = 0.f, sy = 0.f, sz = 0.f, sw = 0.f;
#pragma unroll
    for (int e2 = 0; e2 < 31; e2++) {
      bf16x4 v = bp[e2 * 1024];
      sx += (float)v[0]; sy += (float)v[1]; sz += (float)v[2]; sw += (float)v[3];
    }
    const float inv = 1.0f / 31.0f;
    sx *= inv; sy *= inv; sz *= inv; sw *= inv;
    int o = o4 * 4;
    aggf[r][o] = sx; aggf[r][o + 1] = sy; aggf[r][o + 2] = sz; aggf[r][o + 3] = sw;
    c0b[r][32 + o] = (bf16)sx; c0b[r][33 + o] = (bf16)sy;
    c0b[r][34 + o] = (bf16)sz; c0b[r][35 + o] = (bf16)sw;
  }
  if (tid < 128) {
    int r = tid >> 3, d0 = (tid & 7) * 4;
    int b = q * 16 + r;
#pragma unroll
    for (int k = 0; k < 4; k++) {
      float v = xf[n * 2048 + b * 32 + d0 + k];
      xinf[r][d0 + k] = v;
      c0b[r][d0 + k] = (bf16)v;
    }
  }
  if (t > 0) {
    int r = tid >> 4, cb = (tid & 15) * 6;
    int row = n * 64 + q * 16 + r;
#pragma unroll
    for (int k = 0; k < 6; k++) {
      float v = hnode[row * 96 + cb + k];
      hvf[r][cb + k] = v;
      hvb[r][cb + k] = (bf16)v;
    }
  }
  __syncthreads();
  int wv = tid >> 6, ln = tid & 63, quad = ln >> 4, l16 = ln & 15;
  if (t > 0) {
    int mat = wv >> 1, sel = wv & 1;
    const bf16(*Ab)[112] = mat ? hvb : c0b;
    bf16x8 af[3];
#pragma unroll
    for (int kf = 0; kf < 3; kf++)
      af[kf] = *(const bf16x8*)&Ab[l16][kf * 32 + quad * 8];
    const bf16* W = GN + mat * 27648;
    f32x4 accn[9];
#pragma unroll
    for (int q2 = 0; q2 < 9; q2++) { f32x4 zz = {0.f,0.f,0.f,0.f}; accn[q2] = zz; }
#pragma unroll
    for (int nt2 = 0; nt2 < 9; nt2++) {
      int nt = sel * 9 + nt2;
#pragma unroll
      for (int kf = 0; kf < 3; kf++) {
        bf16x8 bfrag = *(const bf16x8*)&W[((nt * 3 + kf) * 64 + ln) * 8];
        accn[nt2] = mfma_bf16(af[kf], bfrag, accn[nt2]);
      }
    }
#pragma unroll
    for (int nt2 = 0; nt2 < 9; nt2++) {
      int col = (sel * 9 + nt2) * 16 + l16;
#pragma unroll
      for (int rr = 0; rr < 4; rr++)
        gsum[mat][quad * 4 + rr][col] = accn[nt2][rr];
    }
  }
  __syncthreads();
  {
    int r = tid >> 4, cb = (tid & 15) * 6;
    int row = n * 64 + q * 16 + r;
#pragma unroll
    for (int k = 0; k < 6; k++) {
      int c = cb + k;
      float v;
      if (t > 0) {
        float xr = gsum[0][r][c] + gnbi[c] + gsum[1][r][c] + gnbh[c];
        float xi = gsum[0][r][96 + c] + gnbi[96 + c] + gsum[1][r][96 + c] + gnbh[96 + c];
        float xn = gsum[0][r][192 + c] + gnbi[192 + c];
        float hn = gsum[1][r][192 + c] + gnbh[192 + c];
        float rg = sigm(xr);
        float ig = sigm(xi);
        float ng = tanh_f(xn + rg * hn);
        v = (1.0f - ig) * ng + ig * hvf[r][c];
      } else {
        v = (c < 32) ? xinf[r][c] : aggf[r][c - 32];
      }
      cnb[r][c] = (bf16)v;
      hnode[row * 96 + c] = v;
    }
  }
  __syncthreads();
  {
    bf16x8 af3[3];
#pragma unroll
    for (int kf = 0; kf < 3; kf++)
      af3[kf] = *(const bf16x8*)&cnb[l16][kf * 32 + quad * 8];
    f32x4 accn = {0.f, 0.f, 0.f, 0.f};
#pragma unroll
    for (int kf = 0; kf < 3; kf++) {
      bf16x8 bfrag = *(const bf16x8*)&OW1[((wv * 3 + kf) * 64 + ln) * 8];
      accn = mfma_bf16(af3[kf], bfrag, accn);
    }
    int col = wv * 16 + l16;
    float bias = ob1[col];
#pragma unroll
    for (int rr = 0; rr < 4; rr++) {
      float vv = accn[rr] + bias;
      s1b[quad * 4 + rr][col] = (bf16)(vv > 0.f ? vv : 0.f);
    }
  }
  __syncthreads();
  {
    bf16x8 af2[2];
#pragma unroll
    for (int kf = 0; kf < 2; kf++)
      af2[kf] = *(const bf16x8*)&s1b[l16][kf * 32 + quad * 8];
    f32x4 accn = {0.f, 0.f, 0.f, 0.f};
#pragma unroll
    for (int kf = 0; kf < 2; kf++) {
      bf16x8 bfrag = *(const bf16x8*)&OW2[((wv * 2 + kf) * 64 + ln) * 8];
      accn = mfma_bf16(af2[kf], bfrag, accn);
    }
    int col = wv * 16 + l16;
    float bias = ob2[col];
#pragma unroll
    for (int rr = 0; rr < 4; rr++) {
      float vv = accn[rr] + bias;
      s2b[quad * 4 + rr][col] = (bf16)(vv > 0.f ? vv : 0.f);
    }
  }
  __syncthreads();
  if (wv < 2) {
    bf16x8 af2[2];
#pragma unroll
    for (int kf = 0; kf < 2; kf++)
      af2[kf] = *(const bf16x8*)&s2b[l16][kf * 32 + quad * 8];
    f32x4 accn = {0.f, 0.f, 0.f, 0.f};
#pragma unroll
    for (int kf = 0; kf < 2; kf++) {
      bf16x8 bfrag = *(const bf16x8*)&OW3[((wv * 2 + kf) * 64 + ln) * 8];
      accn = mfma_bf16(af2[kf], bfrag, accn);
    }
    int d = wv * 16 + l16;
    float bias = ob3[d];
#pragma unroll
    for (int rr = 0; rr < 4; rr++) {
      int r = quad * 4 + rr;
      int b = q * 16 + r;
      float xm = xinf[r][d] + accn[rr] + bias;
      int base = (b * 32 + n) * 32 + d;
      out[524288 + base * 16 + t] = xm;
      out[1572864 + base * 16 + t] = xm;
      if (t >= NSTEP) out[base * 8 + (t - NSTEP)] = xm;
      float vnext = (t + 1 < NSTEP) ? x[base * 8 + (t + 1)] : xm;
      xf[n * 2048 + b * 32 + d] = vnext;
      xnb[r][d] = (bf16)vnext;
    }
  }
  __syncthreads();
  // --- fused PQ for next step: this block's 16 batch rows of node n ---
  {
    bf16x8 xfrag = *(const bf16x8*)&xnb[l16][quad * 8];
    bf16* pqbase = PQ + ((size_t)(n * 64 + q * 16)) * 384;
#pragma unroll
    for (int i2 = 0; i2 < 6; i2++) {
      int c2 = wv * 6 + i2, nt = c2 >> 1, kf = c2 & 1;
      bf16x8 bfrag = *(const bf16x8*)&B1[(nt * 2 + kf) * 512 + ln * 8];
      f32x4 acc = {0.f, 0.f, 0.f, 0.f};
      acc = mfma_bf16(xfrag, bfrag, acc);
      int col = nt * 16 + l16;
      float badd = kf ? 0.f : mb1[col];
#pragma unroll
      for (int rr = 0; rr < 4; rr++)
        pqbase[(quad * 4 + rr) * 384 + kf * 192 + col] = (bf16)(acc[rr] + badd);
    }
  }
}

extern "C" void kernel_launch(void* const* d_in, const int* in_sizes, int n_in,
                              void* d_out, int out_size, void* d_ws, size_t ws_size,
                              hipStream_t stream) {
  const float* x     = (const float*)d_in[0];
  const float* z     = (const float*)d_in[1];
  const int*   es    = (const int*)d_in[2];
  const float* msgW1 = (const float*)d_in[6];
  const float* msgb1 = (const float*)d_in[7];
  const float* msgW2 = (const float*)d_in[8];
  const float* msgb2 = (const float*)d_in[9];
  const float* oW1   = (const float*)d_in[10];
  const float* ob1   = (const float*)d_in[11];
  const float* oW2   = (const float*)d_in[12];
  const float* ob2   = (const float*)d_in[13];
  const float* oW3   = (const float*)d_in[14];
  const float* ob3   = (const float*)d_in[15];
  const float* geWi  = (const float*)d_in[16];
  const float* gebi  = (const float*)d_in[17];
  const float* geWh  = (const float*)d_in[18];
  const float* gebh  = (const float*)d_in[19];
  const float* gnWi  = (const float*)d_in[20];
  const float* gnbi  = (const float*)d_in[21];
  const float* gnWh  = (const float*)d_in[22];
  const float* gnbh  = (const float*)d_in[23];
  float* out = (float*)d_out;

  char* p = (char*)d_ws;
  bf16*  hed   = (bf16*)p;   p += (size_t)NE * 4096 * 2;   // 8.1 MB
  float* xf    = (float*)p;  p += 65536 * 4;
  bf16*  xb    = (bf16*)p;   p += 65536 * 2;
  float* hnode = (float*)p;  p += 196608 * 4;
  bf16*  PQ    = (bf16*)p;   p += (size_t)32 * 64 * 384 * 2;  // 1.5 MB
  bf16*  B1sw  = (bf16*)p;   p += 12288 * 2;
  bf16*  B2sw  = (bf16*)p;   p += 12288 * 2;
  bf16*  GIsw  = (bf16*)p;   p += 12288 * 2;
  bf16*  GHsw  = (bf16*)p;   p += 12288 * 2;
  bf16*  GNsw  = (bf16*)p;   p += 55296 * 2;
  bf16*  OW1s  = (bf16*)p;   p += 6144 * 2;
  bf16*  OW2s  = (bf16*)p;   p += 4096 * 2;
  bf16*  OW3s  = (bf16*)p;   p += 2048 * 2;

  prep_weights<<<204, 256, 0, stream>>>(msgW1, msgW2, geWi, geWh, gnWi, gnWh,
                                        oW1, oW2, oW3,
                                        B1sw, B2sw, GIsw, GHsw, GNsw,
                                        OW1s, OW2s, OW3s);
  copy_x<<<256, 256, 0, stream>>>(x, xf, xb);
  pq_init<<<32, 256, 0, stream>>>(xb, B1sw, msgb1, PQ);

  for (int t = 0; t < NTT; t++) {
    edge_step<<<NE / 2, 512, 0, stream>>>(PQ, es, z, B2sw, msgb2,
                                          GIsw, GHsw, gebi, gebh, hed, t);
    node_kernel<<<128, 256, 0, stream>>>(x, hed, xf, hnode, GNsw, gnbi, gnbh,
                                         OW1s, ob1, OW2s, ob2, OW3s, ob3,
                                         B1sw, msgb1, PQ, out, t);
  }
}

// Round 7
// 602.590 us; speedup vs baseline: 1.0840x; 1.0840x over previous
//
#include <hip/hip_runtime.h>
#include <hip/hip_bf16.h>

// Problem dims
#define NNODE 32
#define NB    64
#define NDIM  32
#define NSTEP 8
#define NE    992
#define NTT   16

typedef __bf16 bf16;
typedef __attribute__((ext_vector_type(8))) __bf16 bf16x8;
typedef __attribute__((ext_vector_type(4))) __bf16 bf16x4;
typedef __attribute__((ext_vector_type(4))) float  f32x4;

__device__ __forceinline__ f32x4 mfma_bf16(bf16x8 a, bf16x8 b, f32x4 c) {
  return __builtin_amdgcn_mfma_f32_16x16x32_bf16(a, b, c, 0, 0, 0);
}
__device__ __forceinline__ float sigm(float x) { return 1.0f / (1.0f + __expf(-x)); }
__device__ __forceinline__ float tanh_f(float x) {
  x = fminf(fmaxf(x, -15.0f), 15.0f);
  float e = __expf(2.0f * x);
  return (e - 1.0f) / (e + 1.0f);
}

// ---------------------------------------------------------------------------
// Swizzle all weights into MFMA B-fragment bf16 order (round-3 validated).
// ---------------------------------------------------------------------------
__global__ void prep_weights(
    const float* __restrict__ msgW1, const float* __restrict__ msgW2,
    const float* __restrict__ geWi,  const float* __restrict__ geWh,
    const float* __restrict__ gnWi,  const float* __restrict__ gnWh,
    const float* __restrict__ oW1,   const float* __restrict__ oW2,
    const float* __restrict__ oW3,
    bf16* __restrict__ B1, bf16* __restrict__ B2,
    bf16* __restrict__ GI, bf16* __restrict__ GH,
    bf16* __restrict__ GN,
    bf16* __restrict__ OW1s, bf16* __restrict__ OW2s, bf16* __restrict__ OW3s) {
  int u = blockIdx.x * 256 + threadIdx.x;
  if (u < 12288) {
    int k = u >> 12, i = (u >> 6) & 63, h = u & 63;
    int kf = i >> 5, quad = (i >> 3) & 3, j = i & 7;
    int nn = k * 64 + h, nt = nn >> 4, lane = quad * 16 + (nn & 15);
    int slot = ((nt * 2 + kf) * 64 + lane) * 8 + j;
    B1[slot] = (bf16)msgW1[u];
    GI[slot] = (bf16)geWi[u];
    GH[slot] = (bf16)geWh[u];
    int ntl = h >> 4, lane2 = quad * 16 + (h & 15);
    int slot2 = k * 4096 + ((ntl * 2 + kf) * 64 + lane2) * 8 + j;
    B2[slot2] = (bf16)msgW2[u];
  } else if (u < 39936) {
    int v = u - 12288;
    int kk = v / 9216, rem = v % 9216, i = rem / 96, h = rem % 96;
    int kf = i >> 5, loc = i & 31, quad = loc >> 3, j = loc & 7;
    int nn = kk * 96 + h, nt = nn >> 4, lane = quad * 16 + (nn & 15);
    int slot = ((nt * 3 + kf) * 64 + lane) * 8 + j;
    GN[slot]         = (bf16)gnWi[v];
    GN[27648 + slot] = (bf16)gnWh[v];
  } else if (u < 46080) {
    int v = u - 39936; int i = v >> 6, h = v & 63;
    int kf = i >> 5, loc = i & 31, quad = loc >> 3, j = loc & 7;
    int nt = h >> 4, lane = quad * 16 + (h & 15);
    OW1s[((nt * 3 + kf) * 64 + lane) * 8 + j] = (bf16)oW1[v];
  } else if (u < 50176) {
    int v = u - 46080; int i = v >> 6, h = v & 63;
    int kf = i >> 5, quad = (i >> 3) & 3, j = i & 7;
    int nt = h >> 4, lane = quad * 16 + (h & 15);
    OW2s[((nt * 2 + kf) * 64 + lane) * 8 + j] = (bf16)oW2[v];
  } else if (u < 52224) {
    int v = u - 50176; int i = v >> 5, h = v & 31;
    int kf = i >> 5, quad = (i >> 3) & 3, j = i & 7;
    int nt = h >> 4, lane = quad * 16 + (h & 15);
    OW3s[((nt * 2 + kf) * 64 + lane) * 8 + j] = (bf16)oW3[v];
  }
}

// Initial input (t=0) into xf (fp32) + xb (bf16), layout [n][b][d].
__global__ void copy_x(const float* __restrict__ x, float* __restrict__ xf,
                       bf16* __restrict__ xb) {
  int u = blockIdx.x * 256 + threadIdx.x;  // 65536
  int n = u >> 11, b = (u >> 5) & 63, d = u & 31;
  float v = x[((b * 32 + n) * 32 + d) * 8 + 0];
  xf[u] = v;
  xb[u] = (bf16)v;
}

// ---------------------------------------------------------------------------
// Edge step v7: R1 v4 + entry-staged hed (Hh in LDS). The GRU phase's two
// late global reads of hed (A-fragments + hv scalars) were synchronized
// ~600-900-cycle stalls after the mix barrier; hed depends on nothing
// computed in-kernel, so its load now overlaps the entry staging batch.
// LDS 74.2 KB <= 80 KB -> still 2 blocks/CU.
// ---------------------------------------------------------------------------
__global__ __launch_bounds__(512, 4) void edge_step(
    const bf16* __restrict__ xb, const int* __restrict__ es,
    const float* __restrict__ z,
    const bf16* __restrict__ B1, const bf16* __restrict__ B2,
    const float* __restrict__ mb1, const float* __restrict__ mb2,
    const bf16* __restrict__ GI, const bf16* __restrict__ GH,
    const float* __restrict__ gbi, const float* __restrict__ gbh,
    bf16* __restrict__ hed, int t) {
  __shared__ __align__(16) char scrbuf[51200];
  __shared__ float zL[2][64][3];
  __shared__ float biasL[768];  // mb1 | mb2 | gbi | gbh (192 each)
  __shared__ __align__(16) bf16 Hh[2][64][72];  // old edge state (staged at entry)
  bf16 (*A)[64][72]   = (bf16(*)[64][72])scrbuf;    // inputs / mix / state
  bf16 (*A2)[64][200] = (bf16(*)[64][200])scrbuf;   // h1 (aliases A)

  int e0 = blockIdx.x * 2, tid = threadIdx.x;
  int c0_ = es[e0],     r0 = es[NE + e0];
  int c1_ = es[e0 + 1], r1 = es[NE + e0 + 1];
  for (int u = tid; u < 768; u += 512)
    biasL[u] = (u < 192) ? mb1[u] : (u < 384) ? mb2[u - 192]
             : (u < 576) ? gbi[u - 384] : gbh[u - 576];
  for (int u = tid; u < 384; u += 512) {
    int pe = u / 192, rem = u % 192, b = rem / 3, k = rem % 3;
    zL[pe][b][k] = z[(b * NE + e0 + pe) * 3 + k];
  }
  for (int u = tid; u < 1024; u += 512) {
    int pe = u >> 9, c = u & 511;
    int b = c >> 3, i8 = c & 7;
    int nrow = pe ? r1 : r0, ncol = pe ? c1_ : c0_;
    const bf16* src = (i8 < 4) ? (xb + nrow * 2048 + b * 32 + i8 * 8)
                               : (xb + ncol * 2048 + b * 32 + (i8 - 4) * 8);
    *(bf16x8*)&A[pe][b][i8 * 8] = *(const bf16x8*)src;
  }
  if (t > 0) {  // stage old state; latency overlaps the staging batch above
    for (int u = tid; u < 1024; u += 512) {
      int pe = u >> 9, c = u & 511;
      int b = c >> 3, j = c & 7;
      *(bf16x8*)&Hh[pe][b][j * 8] =
          *(const bf16x8*)(hed + (e0 + pe) * 4096 + b * 64 + j * 8);
    }
  }
  __syncthreads();
  int wv = tid >> 6, ln = tid & 63, quad = ln >> 4, l16 = ln & 15;
  int rg = wv & 3, cg = wv >> 2;       // row-group 0..3, col-group 0..1
  int m = rg * 16 + l16;
  bf16x8 af[2][2];
#pragma unroll
  for (int pe = 0; pe < 2; pe++)
#pragma unroll
    for (int kf = 0; kf < 2; kf++)
      af[pe][kf] = *(const bf16x8*)&A[pe][m][kf * 32 + quad * 8];
  __syncthreads();  // A dead -> A2 may overwrite
  // ---- layer 1: [64x64] @ [64x192]; this wave does 6 of the 12 nt-tiles ----
  f32x4 acc1[2][6];
#pragma unroll
  for (int pe = 0; pe < 2; pe++)
#pragma unroll
    for (int q = 0; q < 6; q++) { f32x4 zz = {0.f,0.f,0.f,0.f}; acc1[pe][q] = zz; }
#pragma unroll
  for (int j = 0; j < 6; j++) {
    int nt = cg * 6 + j;
    bf16x8 w0 = *(const bf16x8*)&B1[(nt * 2 + 0) * 512 + ln * 8];
    bf16x8 w1 = *(const bf16x8*)&B1[(nt * 2 + 1) * 512 + ln * 8];
#pragma unroll
    for (int pe = 0; pe < 2; pe++) {
      acc1[pe][j] = mfma_bf16(af[pe][0], w0, acc1[pe][j]);
      acc1[pe][j] = mfma_bf16(af[pe][1], w1, acc1[pe][j]);
    }
  }
#pragma unroll
  for (int j = 0; j < 6; j++) {
    int nt = cg * 6 + j;
    int n = nt * 16 + l16;
    float bias = biasL[n];
#pragma unroll
    for (int pe = 0; pe < 2; pe++)
#pragma unroll
      for (int r = 0; r < 4; r++) {
        float v = acc1[pe][j][r] + bias;
        A2[pe][rg * 16 + quad * 4 + r][n] = (bf16)(v > 0.f ? v : 0.f);
      }
  }
  __syncthreads();
  // ---- layer 2: per-type [64x64] blocks; this wave does out-tiles {2cg,2cg+1} ----
  f32x4 acc2[2][3][2];  // [pe][kt][oi]
#pragma unroll
  for (int pe = 0; pe < 2; pe++)
#pragma unroll
    for (int kt = 0; kt < 3; kt++)
#pragma unroll
      for (int oi = 0; oi < 2; oi++) { f32x4 zz = {0.f,0.f,0.f,0.f}; acc2[pe][kt][oi] = zz; }
#pragma unroll
  for (int kt = 0; kt < 3; kt++) {
    bf16x8 a2f[2][2];
#pragma unroll
    for (int pe = 0; pe < 2; pe++)
#pragma unroll
      for (int kf = 0; kf < 2; kf++)
        a2f[pe][kf] = *(const bf16x8*)&A2[pe][m][kt * 64 + kf * 32 + quad * 8];
#pragma unroll
    for (int oi = 0; oi < 2; oi++) {
      int ot = cg * 2 + oi;
      bf16x8 w0 = *(const bf16x8*)&B2[kt * 4096 + (ot * 2 + 0) * 512 + ln * 8];
      bf16x8 w1 = *(const bf16x8*)&B2[kt * 4096 + (ot * 2 + 1) * 512 + ln * 8];
#pragma unroll
      for (int pe = 0; pe < 2; pe++) {
        acc2[pe][kt][oi] = mfma_bf16(a2f[pe][0], w0, acc2[pe][kt][oi]);
        acc2[pe][kt][oi] = mfma_bf16(a2f[pe][1], w1, acc2[pe][kt][oi]);
      }
    }
  }
  __syncthreads();  // A2 dead -> A (mix/state) may overwrite
  // ---- mix with z, /K -> write into A (own rows x own cols) ----
#pragma unroll
  for (int pe = 0; pe < 2; pe++)
#pragma unroll
    for (int r = 0; r < 4; r++) {
      int b = rg * 16 + quad * 4 + r;
      float z0 = zL[pe][b][0], z1 = zL[pe][b][1], z2 = zL[pe][b][2];
#pragma unroll
      for (int oi = 0; oi < 2; oi++) {
        int o = (cg * 2 + oi) * 16 + l16;
        float h0 = acc2[pe][0][oi][r] + biasL[192 + o];       h0 = h0 > 0.f ? h0 : 0.f;
        float h1 = acc2[pe][1][oi][r] + biasL[192 + 64 + o];  h1 = h1 > 0.f ? h1 : 0.f;
        float h2 = acc2[pe][2][oi][r] + biasL[192 + 128 + o]; h2 = h2 > 0.f ? h2 : 0.f;
        A[pe][b][o] = (bf16)((h0 * z0 + h1 * z1 + h2 * z2) * (1.0f / 3.0f));
      }
    }
  if (t > 0) {
    __syncthreads();
    // ---- edge GRU: mix (LDS A) + old state (LDS Hh) ----
    bf16x8 ai[2][2], ah[2][2];
#pragma unroll
    for (int pe = 0; pe < 2; pe++)
#pragma unroll
      for (int kf = 0; kf < 2; kf++) {
        ai[pe][kf] = *(const bf16x8*)&A[pe][m][kf * 32 + quad * 8];
        ah[pe][kf] = *(const bf16x8*)&Hh[pe][m][kf * 32 + quad * 8];
      }
    // process one 16-wide gate-tile at a time (keeps live accs at 8 f32x4)
#pragma unroll
    for (int oi = 0; oi < 2; oi++) {
      int ot = cg * 2 + oi;
      f32x4 gr[2], gi2[2], gni2[2], gnh2[2];
#pragma unroll
      for (int pe = 0; pe < 2; pe++) {
        f32x4 zz = {0.f,0.f,0.f,0.f};
        gr[pe] = zz; gi2[pe] = zz; gni2[pe] = zz; gnh2[pe] = zz;
      }
#pragma unroll
      for (int g = 0; g < 2; g++) {     // g=0: r-gate (nt=ot), g=1: i-gate (nt=4+ot)
        int nt = g * 4 + ot;
        bf16x8 wi0 = *(const bf16x8*)&GI[(nt * 2 + 0) * 512 + ln * 8];
        bf16x8 wi1 = *(const bf16x8*)&GI[(nt * 2 + 1) * 512 + ln * 8];
        bf16x8 wh0 = *(const bf16x8*)&GH[(nt * 2 + 0) * 512 + ln * 8];
        bf16x8 wh1 = *(const bf16x8*)&GH[(nt * 2 + 1) * 512 + ln * 8];
#pragma unroll
        for (int pe = 0; pe < 2; pe++) {
          f32x4 a = g ? gi2[pe] : gr[pe];
          a = mfma_bf16(ai[pe][0], wi0, a);
          a = mfma_bf16(ai[pe][1], wi1, a);
          a = mfma_bf16(ah[pe][0], wh0, a);
          a = mfma_bf16(ah[pe][1], wh1, a);
          if (g) gi2[pe] = a; else gr[pe] = a;
        }
      }
      {                                  // n-gate (nt=8+ot): i-part and h-part kept apart
        int nt = 8 + ot;
        bf16x8 wi0 = *(const bf16x8*)&GI[(nt * 2 + 0) * 512 + ln * 8];
        bf16x8 wi1 = *(const bf16x8*)&GI[(nt * 2 + 1) * 512 + ln * 8];
        bf16x8 wh0 = *(const bf16x8*)&GH[(nt * 2 + 0) * 512 + ln * 8];
        bf16x8 wh1 = *(const bf16x8*)&GH[(nt * 2 + 1) * 512 + ln * 8];
#pragma unroll
        for (int pe = 0; pe < 2; pe++) {
          gni2[pe] = mfma_bf16(ai[pe][0], wi0, gni2[pe]);
          gni2[pe] = mfma_bf16(ai[pe][1], wi1, gni2[pe]);
          gnh2[pe] = mfma_bf16(ah[pe][0], wh0, gnh2[pe]);
          gnh2[pe] = mfma_bf16(ah[pe][1], wh1, gnh2[pe]);
        }
      }
#pragma unroll
      for (int pe = 0; pe < 2; pe++)
#pragma unroll
        for (int r = 0; r < 4; r++) {
          int b = rg * 16 + quad * 4 + r;
          int o = ot * 16 + l16;
          float xr = gr[pe][r]   + biasL[384 + o]       + biasL[576 + o];
          float xi = gi2[pe][r]  + biasL[384 + 64 + o]  + biasL[576 + 64 + o];
          float xn = gni2[pe][r] + biasL[384 + 128 + o];
          float hn = gnh2[pe][r] + biasL[576 + 128 + o];
          float rgt = sigm(xr);
          float ig  = sigm(xi);
          float ng  = tanh_f(xn + rgt * hn);
          float hv  = (float)Hh[pe][b][o];
          A[pe][b][o] = (bf16)((1.0f - ig) * ng + ig * hv);
        }
    }
  }
  __syncthreads();
  // coalesced writeback of new state
  for (int u = tid; u < 1024; u += 512) {
    int pe = u >> 9, c = u & 511;
    int b = c >> 3, j = c & 7;
    *(bf16x8*)(hed + (e0 + pe) * 4096 + b * 64 + j * 8) = *(const bf16x8*)&A[pe][b][j * 8];
  }
}

// ---------------------------------------------------------------------------
// Node kernel (round-1 validated 256-thread version, verbatim): scatter-mean
// agg + node GRU (MFMA) + 3-layer out-MLP. Also prepares next step's input.
// ---------------------------------------------------------------------------
__global__ __launch_bounds__(256) void node_kernel(
    const float* __restrict__ x, const bf16* __restrict__ hed,
    float* __restrict__ xf, bf16* __restrict__ xb, float* __restrict__ hnode,
    const bf16* __restrict__ GN,
    const float* __restrict__ gnbi, const float* __restrict__ gnbh,
    const bf16* __restrict__ OW1, const float* __restrict__ ob1,
    const bf16* __restrict__ OW2, const float* __restrict__ ob2,
    const bf16* __restrict__ OW3, const float* __restrict__ ob3,
    float* __restrict__ out, int t) {
  __shared__ float aggf[16][64];
  __shared__ float xinf[16][32];
  __shared__ float hvf[16][96];
  __shared__ __align__(16) bf16 c0b[16][112];
  __shared__ __align__(16) bf16 hvb[16][112];
  __shared__ float gsum[2][16][290];
  __shared__ __align__(16) bf16 cnb[16][112];
  __shared__ __align__(16) bf16 s1b[16][112];
  __shared__ __align__(16) bf16 s2b[16][112];
  int nq = blockIdx.x, n = nq >> 2, q = nq & 3;
  int tid = threadIdx.x;
  {
    int r = tid >> 4, o4 = tid & 15;
    const bf16x4* bp = (const bf16x4*)hed + (size_t)n * 31 * 1024 + (q * 16 + r) * 16 + o4;
    float sx = 0.f, sy = 0.f, sz = 0.f, sw = 0.f;
#pragma unroll
    for (int e2 = 0; e2 < 31; e2++) {
      bf16x4 v = bp[e2 * 1024];
      sx += (float)v[0]; sy += (float)v[1]; sz += (float)v[2]; sw += (float)v[3];
    }
    const float inv = 1.0f / 31.0f;
    sx *= inv; sy *= inv; sz *= inv; sw *= inv;
    int o = o4 * 4;
    aggf[r][o] = sx; aggf[r][o + 1] = sy; aggf[r][o + 2] = sz; aggf[r][o + 3] = sw;
    c0b[r][32 + o] = (bf16)sx; c0b[r][33 + o] = (bf16)sy;
    c0b[r][34 + o] = (bf16)sz; c0b[r][35 + o] = (bf16)sw;
  }
  if (tid < 128) {
    int r = tid >> 3, d0 = (tid & 7) * 4;
    int b = q * 16 + r;
#pragma unroll
    for (int k = 0; k < 4; k++) {
      float v = xf[n * 2048 + b * 32 + d0 + k];
      xinf[r][d0 + k] = v;
      c0b[r][d0 + k] = (bf16)v;
    }
  }
  if (t > 0) {
    int r = tid >> 4, cb = (tid & 15) * 6;
    int row = n * 64 + q * 16 + r;
#pragma unroll
    for (int k = 0; k < 6; k++) {
      float v = hnode[row * 96 + cb + k];
      hvf[r][cb + k] = v;
      hvb[r][cb + k] = (bf16)v;
    }
  }
  __syncthreads();
  int wv = tid >> 6, ln = tid & 63, quad = ln >> 4, l16 = ln & 15;
  if (t > 0) {
    int mat = wv >> 1, sel = wv & 1;
    const bf16(*Ab)[112] = mat ? hvb : c0b;
    bf16x8 af[3];
#pragma unroll
    for (int kf = 0; kf < 3; kf++)
      af[kf] = *(const bf16x8*)&Ab[l16][kf * 32 + quad * 8];
    const bf16* W = GN + mat * 27648;
    f32x4 accn[9];
#pragma unroll
    for (int q2 = 0; q2 < 9; q2++) { f32x4 zz = {0.f,0.f,0.f,0.f}; accn[q2] = zz; }
#pragma unroll
    for (int nt2 = 0; nt2 < 9; nt2++) {
      int nt = sel * 9 + nt2;
#pragma unroll
      for (int kf = 0; kf < 3; kf++) {
        bf16x8 bfrag = *(const bf16x8*)&W[((nt * 3 + kf) * 64 + ln) * 8];
        accn[nt2] = mfma_bf16(af[kf], bfrag, accn[nt2]);
      }
    }
#pragma unroll
    for (int nt2 = 0; nt2 < 9; nt2++) {
      int col = (sel * 9 + nt2) * 16 + l16;
#pragma unroll
      for (int rr = 0; rr < 4; rr++)
        gsum[mat][quad * 4 + rr][col] = accn[nt2][rr];
    }
  }
  __syncthreads();
  {
    int r = tid >> 4, cb = (tid & 15) * 6;
    int row = n * 64 + q * 16 + r;
#pragma unroll
    for (int k = 0; k < 6; k++) {
      int c = cb + k;
      float v;
      if (t > 0) {
        float xr = gsum[0][r][c] + gnbi[c] + gsum[1][r][c] + gnbh[c];
        float xi = gsum[0][r][96 + c] + gnbi[96 + c] + gsum[1][r][96 + c] + gnbh[96 + c];
        float xn = gsum[0][r][192 + c] + gnbi[192 + c];
        float hn = gsum[1][r][192 + c] + gnbh[192 + c];
        float rg = sigm(xr);
        float ig = sigm(xi);
        float ng = tanh_f(xn + rg * hn);
        v = (1.0f - ig) * ng + ig * hvf[r][c];
      } else {
        v = (c < 32) ? xinf[r][c] : aggf[r][c - 32];
      }
      cnb[r][c] = (bf16)v;
      hnode[row * 96 + c] = v;
    }
  }
  __syncthreads();
  {
    bf16x8 af3[3];
#pragma unroll
    for (int kf = 0; kf < 3; kf++)
      af3[kf] = *(const bf16x8*)&cnb[l16][kf * 32 + quad * 8];
    f32x4 accn = {0.f, 0.f, 0.f, 0.f};
#pragma unroll
    for (int kf = 0; kf < 3; kf++) {
      bf16x8 bfrag = *(const bf16x8*)&OW1[((wv * 3 + kf) * 64 + ln) * 8];
      accn = mfma_bf16(af3[kf], bfrag, accn);
    }
    int col = wv * 16 + l16;
    float bias = ob1[col];
#pragma unroll
    for (int rr = 0; rr < 4; rr++) {
      float vv = accn[rr] + bias;
      s1b[quad * 4 + rr][col] = (bf16)(vv > 0.f ? vv : 0.f);
    }
  }
  __syncthreads();
  {
    bf16x8 af2[2];
#pragma unroll
    for (int kf = 0; kf < 2; kf++)
      af2[kf] = *(const bf16x8*)&s1b[l16][kf * 32 + quad * 8];
    f32x4 accn = {0.f, 0.f, 0.f, 0.f};
#pragma unroll
    for (int kf = 0; kf < 2; kf++) {
      bf16x8 bfrag = *(const bf16x8*)&OW2[((wv * 2 + kf) * 64 + ln) * 8];
      accn = mfma_bf16(af2[kf], bfrag, accn);
    }
    int col = wv * 16 + l16;
    float bias = ob2[col];
#pragma unroll
    for (int rr = 0; rr < 4; rr++) {
      float vv = accn[rr] + bias;
      s2b[quad * 4 + rr][col] = (bf16)(vv > 0.f ? vv : 0.f);
    }
  }
  __syncthreads();
  if (wv < 2) {
    bf16x8 af2[2];
#pragma unroll
    for (int kf = 0; kf < 2; kf++)
      af2[kf] = *(const bf16x8*)&s2b[l16][kf * 32 + quad * 8];
    f32x4 accn = {0.f, 0.f, 0.f, 0.f};
#pragma unroll
    for (int kf = 0; kf < 2; kf++) {
      bf16x8 bfrag = *(const bf16x8*)&OW3[((wv * 2 + kf) * 64 + ln) * 8];
      accn = mfma_bf16(af2[kf], bfrag, accn);
    }
    int d = wv * 16 + l16;
    float bias = ob3[d];
#pragma unroll
    for (int rr = 0; rr < 4; rr++) {
      int r = quad * 4 + rr;
      int b = q * 16 + r;
      float xm = xinf[r][d] + accn[rr] + bias;
      int base = (b * 32 + n) * 32 + d;
      out[524288 + base * 16 + t] = xm;
      out[1572864 + base * 16 + t] = xm;
      if (t >= NSTEP) out[base * 8 + (t - NSTEP)] = xm;
      float vnext = (t + 1 < NSTEP) ? x[base * 8 + (t + 1)] : xm;
      xf[n * 2048 + b * 32 + d] = vnext;
      xb[n * 2048 + b * 32 + d] = (bf16)vnext;
    }
  }
}

extern "C" void kernel_launch(void* const* d_in, const int* in_sizes, int n_in,
                              void* d_out, int out_size, void* d_ws, size_t ws_size,
                              hipStream_t stream) {
  const float* x     = (const float*)d_in[0];
  const float* z     = (const float*)d_in[1];
  const int*   es    = (const int*)d_in[2];
  const float* msgW1 = (const float*)d_in[6];
  const float* msgb1 = (const float*)d_in[7];
  const float* msgW2 = (const float*)d_in[8];
  const float* msgb2 = (const float*)d_in[9];
  const float* oW1   = (const float*)d_in[10];
  const float* ob1   = (const float*)d_in[11];
  const float* oW2   = (const float*)d_in[12];
  const float* ob2   = (const float*)d_in[13];
  const float* oW3   = (const float*)d_in[14];
  const float* ob3   = (const float*)d_in[15];
  const float* geWi  = (const float*)d_in[16];
  const float* gebi  = (const float*)d_in[17];
  const float* geWh  = (const float*)d_in[18];
  const float* gebh  = (const float*)d_in[19];
  const float* gnWi  = (const float*)d_in[20];
  const float* gnbi  = (const float*)d_in[21];
  const float* gnWh  = (const float*)d_in[22];
  const float* gnbh  = (const float*)d_in[23];
  float* out = (float*)d_out;

  char* p = (char*)d_ws;
  bf16*  hed   = (bf16*)p;   p += (size_t)NE * 4096 * 2;   // 8.1 MB
  float* xf    = (float*)p;  p += 65536 * 4;
  bf16*  xb    = (bf16*)p;   p += 65536 * 2;
  float* hnode = (float*)p;  p += 196608 * 4;
  bf16*  B1sw  = (bf16*)p;   p += 12288 * 2;
  bf16*  B2sw  = (bf16*)p;   p += 12288 * 2;
  bf16*  GIsw  = (bf16*)p;   p += 12288 * 2;
  bf16*  GHsw  = (bf16*)p;   p += 12288 * 2;
  bf16*  GNsw  = (bf16*)p;   p += 55296 * 2;
  bf16*  OW1s  = (bf16*)p;   p += 6144 * 2;
  bf16*  OW2s  = (bf16*)p;   p += 4096 * 2;
  bf16*  OW3s  = (bf16*)p;   p += 2048 * 2;

  prep_weights<<<204, 256, 0, stream>>>(msgW1, msgW2, geWi, geWh, gnWi, gnWh,
                                        oW1, oW2, oW3,
                                        B1sw, B2sw, GIsw, GHsw, GNsw,
                                        OW1s, OW2s, OW3s);
  copy_x<<<256, 256, 0, stream>>>(x, xf, xb);

  for (int t = 0; t < NTT; t++) {
    edge_step<<<NE / 2, 512, 0, stream>>>(xb, es, z, B1sw, B2sw, msgb1, msgb2,
                                          GIsw, GHsw, gebi, gebh, hed, t);
    node_kernel<<<128, 256, 0, stream>>>(x, hed, xf, xb, hnode, GNsw, gnbi, gnbh,
                                         OW1s, ob1, OW2s, ob2, OW3s, ob3,
                                         out, t);
  }
}

// Round 8
// 599.734 us; speedup vs baseline: 1.0892x; 1.0048x over previous
//
#include <hip/hip_runtime.h>
#include <hip/hip_bf16.h>

// Problem dims
#define NNODE 32
#define NB    64
#define NDIM  32
#define NSTEP 8
#define NE    992
#define NTT   16

typedef __bf16 bf16;
typedef __attribute__((ext_vector_type(8))) __bf16 bf16x8;
typedef __attribute__((ext_vector_type(4))) __bf16 bf16x4;
typedef __attribute__((ext_vector_type(4))) float  f32x4;

__device__ __forceinline__ f32x4 mfma_bf16(bf16x8 a, bf16x8 b, f32x4 c) {
  return __builtin_amdgcn_mfma_f32_16x16x32_bf16(a, b, c, 0, 0, 0);
}
__device__ __forceinline__ float sigm(float x) { return 1.0f / (1.0f + __expf(-x)); }
__device__ __forceinline__ float tanh_f(float x) {
  x = fminf(fmaxf(x, -15.0f), 15.0f);
  float e = __expf(2.0f * x);
  return (e - 1.0f) / (e + 1.0f);
}

// ---------------------------------------------------------------------------
// Swizzle all weights into MFMA B-fragment bf16 order (round-3 validated).
// ---------------------------------------------------------------------------
__global__ void prep_weights(
    const float* __restrict__ msgW1, const float* __restrict__ msgW2,
    const float* __restrict__ geWi,  const float* __restrict__ geWh,
    const float* __restrict__ gnWi,  const float* __restrict__ gnWh,
    const float* __restrict__ oW1,   const float* __restrict__ oW2,
    const float* __restrict__ oW3,
    bf16* __restrict__ B1, bf16* __restrict__ B2,
    bf16* __restrict__ GI, bf16* __restrict__ GH,
    bf16* __restrict__ GN,
    bf16* __restrict__ OW1s, bf16* __restrict__ OW2s, bf16* __restrict__ OW3s) {
  int u = blockIdx.x * 256 + threadIdx.x;
  if (u < 12288) {
    int k = u >> 12, i = (u >> 6) & 63, h = u & 63;
    int kf = i >> 5, quad = (i >> 3) & 3, j = i & 7;
    int nn = k * 64 + h, nt = nn >> 4, lane = quad * 16 + (nn & 15);
    int slot = ((nt * 2 + kf) * 64 + lane) * 8 + j;
    B1[slot] = (bf16)msgW1[u];
    GI[slot] = (bf16)geWi[u];
    GH[slot] = (bf16)geWh[u];
    int ntl = h >> 4, lane2 = quad * 16 + (h & 15);
    int slot2 = k * 4096 + ((ntl * 2 + kf) * 64 + lane2) * 8 + j;
    B2[slot2] = (bf16)msgW2[u];
  } else if (u < 39936) {
    int v = u - 12288;
    int kk = v / 9216, rem = v % 9216, i = rem / 96, h = rem % 96;
    int kf = i >> 5, loc = i & 31, quad = loc >> 3, j = loc & 7;
    int nn = kk * 96 + h, nt = nn >> 4, lane = quad * 16 + (nn & 15);
    int slot = ((nt * 3 + kf) * 64 + lane) * 8 + j;
    GN[slot]         = (bf16)gnWi[v];
    GN[27648 + slot] = (bf16)gnWh[v];
  } else if (u < 46080) {
    int v = u - 39936; int i = v >> 6, h = v & 63;
    int kf = i >> 5, loc = i & 31, quad = loc >> 3, j = loc & 7;
    int nt = h >> 4, lane = quad * 16 + (h & 15);
    OW1s[((nt * 3 + kf) * 64 + lane) * 8 + j] = (bf16)oW1[v];
  } else if (u < 50176) {
    int v = u - 46080; int i = v >> 6, h = v & 63;
    int kf = i >> 5, quad = (i >> 3) & 3, j = i & 7;
    int nt = h >> 4, lane = quad * 16 + (h & 15);
    OW2s[((nt * 2 + kf) * 64 + lane) * 8 + j] = (bf16)oW2[v];
  } else if (u < 52224) {
    int v = u - 50176; int i = v >> 5, h = v & 31;
    int kf = i >> 5, quad = (i >> 3) & 3, j = i & 7;
    int nt = h >> 4, lane = quad * 16 + (h & 15);
    OW3s[((nt * 2 + kf) * 64 + lane) * 8 + j] = (bf16)oW3[v];
  }
}

// Initial input (t=0) into xf (fp32) + xb (bf16), layout [n][b][d].
__global__ void copy_x(const float* __restrict__ x, float* __restrict__ xf,
                       bf16* __restrict__ xb) {
  int u = blockIdx.x * 256 + threadIdx.x;  // 65536
  int n = u >> 11, b = (u >> 5) & 63, d = u & 31;
  float v = x[((b * 32 + n) * 32 + d) * 8 + 0];
  xf[u] = v;
  xb[u] = (bf16)v;
}

// ---------------------------------------------------------------------------
// Edge step v8: serial-chain reduction. vs v7:
//  - af A-fragments loaded DIRECTLY from global (per-lane pattern, v5-validated)
//    -> xb staging loop + 2 barriers deleted; entry z/Hh loads overlap L1 MFMAs.
//  - all biases read directly from global (coalesced/broadcast, L2-resident)
//    -> biasL LDS deleted.
//  - mix (t=0) / GRU (t>0) epilogues store h_new straight to hed (C-layout
//    scalar stores; L2 merges 32B segments) -> final barrier + copy deleted.
//  Barriers: 6 -> 3 (t>0), 2 (t=0). LDS 71.2 KB -> still 2 blocks/CU.
// ---------------------------------------------------------------------------
__global__ __launch_bounds__(512, 4) void edge_step(
    const bf16* __restrict__ xb, const int* __restrict__ es,
    const float* __restrict__ z,
    const bf16* __restrict__ B1, const bf16* __restrict__ B2,
    const float* __restrict__ mb1, const float* __restrict__ mb2,
    const bf16* __restrict__ GI, const bf16* __restrict__ GH,
    const float* __restrict__ gbi, const float* __restrict__ gbh,
    bf16* __restrict__ hed, int t) {
  __shared__ __align__(16) char scrbuf[51200];
  __shared__ float zL[2][64][3];
  __shared__ __align__(16) bf16 Hh[2][64][72];  // old edge state (staged at entry)
  bf16 (*A)[64][72]   = (bf16(*)[64][72])scrbuf;    // mix state (t>0 handoff)
  bf16 (*A2)[64][200] = (bf16(*)[64][200])scrbuf;   // h1 (aliases A)

  int e0 = blockIdx.x * 2, tid = threadIdx.x;
  int c0_ = es[e0],     r0 = es[NE + e0];
  int c1_ = es[e0 + 1], r1 = es[NE + e0 + 1];
  int wv = tid >> 6, ln = tid & 63, quad = ln >> 4, l16 = ln & 15;
  int rg = wv & 3, cg = wv >> 2;       // row-group 0..3, col-group 0..1
  int m = rg * 16 + l16;

  // ---- entry staging: z and (t>0) old state. Latency overlaps af + L1. ----
  for (int u = tid; u < 384; u += 512) {
    int pe = u / 192, rem = u % 192, b = rem / 3, k = rem % 3;
    zL[pe][b][k] = z[(b * NE + e0 + pe) * 3 + k];
  }
  if (t > 0) {
    for (int u = tid; u < 1024; u += 512) {
      int pe = u >> 9, c = u & 511;
      int b = c >> 3, j = c & 7;
      *(bf16x8*)&Hh[pe][b][j * 8] =
          *(const bf16x8*)(hed + (e0 + pe) * 4096 + b * 64 + j * 8);
    }
  }

  // ---- A-fragments direct from global (no LDS round trip, no barrier) ----
  bf16x8 af[2][2];
  af[0][0] = *(const bf16x8*)(xb + r0 * 2048 + m * 32 + quad * 8);
  af[0][1] = *(const bf16x8*)(xb + c0_ * 2048 + m * 32 + quad * 8);
  af[1][0] = *(const bf16x8*)(xb + r1 * 2048 + m * 32 + quad * 8);
  af[1][1] = *(const bf16x8*)(xb + c1_ * 2048 + m * 32 + quad * 8);

  // ---- layer 1: [64x64] @ [64x192]; this wave does 6 of the 12 nt-tiles ----
  f32x4 acc1[2][6];
#pragma unroll
  for (int pe = 0; pe < 2; pe++)
#pragma unroll
    for (int q = 0; q < 6; q++) { f32x4 zz = {0.f,0.f,0.f,0.f}; acc1[pe][q] = zz; }
#pragma unroll
  for (int j = 0; j < 6; j++) {
    int nt = cg * 6 + j;
    bf16x8 w0 = *(const bf16x8*)&B1[(nt * 2 + 0) * 512 + ln * 8];
    bf16x8 w1 = *(const bf16x8*)&B1[(nt * 2 + 1) * 512 + ln * 8];
#pragma unroll
    for (int pe = 0; pe < 2; pe++) {
      acc1[pe][j] = mfma_bf16(af[pe][0], w0, acc1[pe][j]);
      acc1[pe][j] = mfma_bf16(af[pe][1], w1, acc1[pe][j]);
    }
  }
#pragma unroll
  for (int j = 0; j < 6; j++) {
    int nt = cg * 6 + j;
    int n = nt * 16 + l16;
    float bias = mb1[n];                  // direct global (coalesced, L2-hot)
#pragma unroll
    for (int pe = 0; pe < 2; pe++)
#pragma unroll
      for (int r = 0; r < 4; r++) {
        float v = acc1[pe][j][r] + bias;
        A2[pe][rg * 16 + quad * 4 + r][n] = (bf16)(v > 0.f ? v : 0.f);
      }
  }
  __syncthreads();  // #1: A2 ready (cross-cg); zL/Hh staging also landed
  // ---- layer 2: per-type [64x64] blocks; this wave does out-tiles {2cg,2cg+1} ----
  f32x4 acc2[2][3][2];  // [pe][kt][oi]
#pragma unroll
  for (int pe = 0; pe < 2; pe++)
#pragma unroll
    for (int kt = 0; kt < 3; kt++)
#pragma unroll
      for (int oi = 0; oi < 2; oi++) { f32x4 zz = {0.f,0.f,0.f,0.f}; acc2[pe][kt][oi] = zz; }
#pragma unroll
  for (int kt = 0; kt < 3; kt++) {
    bf16x8 a2f[2][2];
#pragma unroll
    for (int pe = 0; pe < 2; pe++)
#pragma unroll
      for (int kf = 0; kf < 2; kf++)
        a2f[pe][kf] = *(const bf16x8*)&A2[pe][m][kt * 64 + kf * 32 + quad * 8];
#pragma unroll
    for (int oi = 0; oi < 2; oi++) {
      int ot = cg * 2 + oi;
      bf16x8 w0 = *(const bf16x8*)&B2[kt * 4096 + (ot * 2 + 0) * 512 + ln * 8];
      bf16x8 w1 = *(const bf16x8*)&B2[kt * 4096 + (ot * 2 + 1) * 512 + ln * 8];
#pragma unroll
      for (int pe = 0; pe < 2; pe++) {
        acc2[pe][kt][oi] = mfma_bf16(a2f[pe][0], w0, acc2[pe][kt][oi]);
        acc2[pe][kt][oi] = mfma_bf16(a2f[pe][1], w1, acc2[pe][kt][oi]);
      }
    }
  }
  __syncthreads();  // #2: A2 dead -> A (mix) may overwrite; zL visible
  // ---- mix with z, /K; biases direct from global ----
  float mb2v[3][2];
#pragma unroll
  for (int kt = 0; kt < 3; kt++)
#pragma unroll
    for (int oi = 0; oi < 2; oi++)
      mb2v[kt][oi] = mb2[kt * 64 + (cg * 2 + oi) * 16 + l16];
#pragma unroll
  for (int pe = 0; pe < 2; pe++)
#pragma unroll
    for (int r = 0; r < 4; r++) {
      int b = rg * 16 + quad * 4 + r;
      float z0 = zL[pe][b][0], z1 = zL[pe][b][1], z2 = zL[pe][b][2];
#pragma unroll
      for (int oi = 0; oi < 2; oi++) {
        int o = (cg * 2 + oi) * 16 + l16;
        float h0 = acc2[pe][0][oi][r] + mb2v[0][oi]; h0 = h0 > 0.f ? h0 : 0.f;
        float h1 = acc2[pe][1][oi][r] + mb2v[1][oi]; h1 = h1 > 0.f ? h1 : 0.f;
        float h2 = acc2[pe][2][oi][r] + mb2v[2][oi]; h2 = h2 > 0.f ? h2 : 0.f;
        float val = (h0 * z0 + h1 * z1 + h2 * z2) * (1.0f / 3.0f);
        if (t == 0)
          hed[(e0 + pe) * 4096 + b * 64 + o] = (bf16)val;  // direct store, done
        else
          A[pe][b][o] = (bf16)val;                         // handoff to GRU
      }
    }
  if (t > 0) {
    __syncthreads();  // #3: mix ready (cross-cg)
    // ---- edge GRU: mix (LDS A) + old state (LDS Hh) ----
    bf16x8 ai[2][2], ah[2][2];
#pragma unroll
    for (int pe = 0; pe < 2; pe++)
#pragma unroll
      for (int kf = 0; kf < 2; kf++) {
        ai[pe][kf] = *(const bf16x8*)&A[pe][m][kf * 32 + quad * 8];
        ah[pe][kf] = *(const bf16x8*)&Hh[pe][m][kf * 32 + quad * 8];
      }
#pragma unroll
    for (int oi = 0; oi < 2; oi++) {
      int ot = cg * 2 + oi;
      f32x4 gr[2], gi2[2], gni2[2], gnh2[2];
#pragma unroll
      for (int pe = 0; pe < 2; pe++) {
        f32x4 zz = {0.f,0.f,0.f,0.f};
        gr[pe] = zz; gi2[pe] = zz; gni2[pe] = zz; gnh2[pe] = zz;
      }
#pragma unroll
      for (int g = 0; g < 2; g++) {     // g=0: r-gate (nt=ot), g=1: i-gate (nt=4+ot)
        int nt = g * 4 + ot;
        bf16x8 wi0 = *(const bf16x8*)&GI[(nt * 2 + 0) * 512 + ln * 8];
        bf16x8 wi1 = *(const bf16x8*)&GI[(nt * 2 + 1) * 512 + ln * 8];
        bf16x8 wh0 = *(const bf16x8*)&GH[(nt * 2 + 0) * 512 + ln * 8];
        bf16x8 wh1 = *(const bf16x8*)&GH[(nt * 2 + 1) * 512 + ln * 8];
#pragma unroll
        for (int pe = 0; pe < 2; pe++) {
          f32x4 a = g ? gi2[pe] : gr[pe];
          a = mfma_bf16(ai[pe][0], wi0, a);
          a = mfma_bf16(ai[pe][1], wi1, a);
          a = mfma_bf16(ah[pe][0], wh0, a);
          a = mfma_bf16(ah[pe][1], wh1, a);
          if (g) gi2[pe] = a; else gr[pe] = a;
        }
      }
      {                                  // n-gate (nt=8+ot): i-part and h-part kept apart
        int nt = 8 + ot;
        bf16x8 wi0 = *(const bf16x8*)&GI[(nt * 2 + 0) * 512 + ln * 8];
        bf16x8 wi1 = *(const bf16x8*)&GI[(nt * 2 + 1) * 512 + ln * 8];
        bf16x8 wh0 = *(const bf16x8*)&GH[(nt * 2 + 0) * 512 + ln * 8];
        bf16x8 wh1 = *(const bf16x8*)&GH[(nt * 2 + 1) * 512 + ln * 8];
#pragma unroll
        for (int pe = 0; pe < 2; pe++) {
          gni2[pe] = mfma_bf16(ai[pe][0], wi0, gni2[pe]);
          gni2[pe] = mfma_bf16(ai[pe][1], wi1, gni2[pe]);
          gnh2[pe] = mfma_bf16(ah[pe][0], wh0, gnh2[pe]);
          gnh2[pe] = mfma_bf16(ah[pe][1], wh1, gnh2[pe]);
        }
      }
      int o = ot * 16 + l16;
      float bir = gbi[o],       bhr = gbh[o];
      float bii = gbi[64 + o],  bhi = gbh[64 + o];
      float bin = gbi[128 + o], bhn = gbh[128 + o];
#pragma unroll
      for (int pe = 0; pe < 2; pe++)
#pragma unroll
        for (int r = 0; r < 4; r++) {
          int b = rg * 16 + quad * 4 + r;
          float xr = gr[pe][r]   + bir + bhr;
          float xi = gi2[pe][r]  + bii + bhi;
          float xn = gni2[pe][r] + bin;
          float hn = gnh2[pe][r] + bhn;
          float rgt = sigm(xr);
          float ig  = sigm(xi);
          float ng  = tanh_f(xn + rgt * hn);
          float hv  = (float)Hh[pe][b][o];
          hed[(e0 + pe) * 4096 + b * 64 + o] =
              (bf16)((1.0f - ig) * ng + ig * hv);   // direct store
        }
    }
  }
}

// ---------------------------------------------------------------------------
// Node kernel (round-1 validated 256-thread version, verbatim): scatter-mean
// agg + node GRU (MFMA) + 3-layer out-MLP. Also prepares next step's input.
// ---------------------------------------------------------------------------
__global__ __launch_bounds__(256) void node_kernel(
    const float* __restrict__ x, const bf16* __restrict__ hed,
    float* __restrict__ xf, bf16* __restrict__ xb, float* __restrict__ hnode,
    const bf16* __restrict__ GN,
    const float* __restrict__ gnbi, const float* __restrict__ gnbh,
    const bf16* __restrict__ OW1, const float* __restrict__ ob1,
    const bf16* __restrict__ OW2, const float* __restrict__ ob2,
    const bf16* __restrict__ OW3, const float* __restrict__ ob3,
    float* __restrict__ out, int t) {
  __shared__ float aggf[16][64];
  __shared__ float xinf[16][32];
  __shared__ float hvf[16][96];
  __shared__ __align__(16) bf16 c0b[16][112];
  __shared__ __align__(16) bf16 hvb[16][112];
  __shared__ float gsum[2][16][290];
  __shared__ __align__(16) bf16 cnb[16][112];
  __shared__ __align__(16) bf16 s1b[16][112];
  __shared__ __align__(16) bf16 s2b[16][112];
  int nq = blockIdx.x, n = nq >> 2, q = nq & 3;
  int tid = threadIdx.x;
  {
    int r = tid >> 4, o4 = tid & 15;
    const bf16x4* bp = (const bf16x4*)hed + (size_t)n * 31 * 1024 + (q * 16 + r) * 16 + o4;
    float sx = 0.f, sy = 0.f, sz = 0.f, sw = 0.f;
#pragma unroll
    for (int e2 = 0; e2 < 31; e2++) {
      bf16x4 v = bp[e2 * 1024];
      sx += (float)v[0]; sy += (float)v[1]; sz += (float)v[2]; sw += (float)v[3];
    }
    const float inv = 1.0f / 31.0f;
    sx *= inv; sy *= inv; sz *= inv; sw *= inv;
    int o = o4 * 4;
    aggf[r][o] = sx; aggf[r][o + 1] = sy; aggf[r][o + 2] = sz; aggf[r][o + 3] = sw;
    c0b[r][32 + o] = (bf16)sx; c0b[r][33 + o] = (bf16)sy;
    c0b[r][34 + o] = (bf16)sz; c0b[r][35 + o] = (bf16)sw;
  }
  if (tid < 128) {
    int r = tid >> 3, d0 = (tid & 7) * 4;
    int b = q * 16 + r;
#pragma unroll
    for (int k = 0; k < 4; k++) {
      float v = xf[n * 2048 + b * 32 + d0 + k];
      xinf[r][d0 + k] = v;
      c0b[r][d0 + k] = (bf16)v;
    }
  }
  if (t > 0) {
    int r = tid >> 4, cb = (tid & 15) * 6;
    int row = n * 64 + q * 16 + r;
#pragma unroll
    for (int k = 0; k < 6; k++) {
      float v = hnode[row * 96 + cb + k];
      hvf[r][cb + k] = v;
      hvb[r][cb + k] = (bf16)v;
    }
  }
  __syncthreads();
  int wv = tid >> 6, ln = tid & 63, quad = ln >> 4, l16 = ln & 15;
  if (t > 0) {
    int mat = wv >> 1, sel = wv & 1;
    const bf16(*Ab)[112] = mat ? hvb : c0b;
    bf16x8 af[3];
#pragma unroll
    for (int kf = 0; kf < 3; kf++)
      af[kf] = *(const bf16x8*)&Ab[l16][kf * 32 + quad * 8];
    const bf16* W = GN + mat * 27648;
    f32x4 accn[9];
#pragma unroll
    for (int q2 = 0; q2 < 9; q2++) { f32x4 zz = {0.f,0.f,0.f,0.f}; accn[q2] = zz; }
#pragma unroll
    for (int nt2 = 0; nt2 < 9; nt2++) {
      int nt = sel * 9 + nt2;
#pragma unroll
      for (int kf = 0; kf < 3; kf++) {
        bf16x8 bfrag = *(const bf16x8*)&W[((nt * 3 + kf) * 64 + ln) * 8];
        accn[nt2] = mfma_bf16(af[kf], bfrag, accn[nt2]);
      }
    }
#pragma unroll
    for (int nt2 = 0; nt2 < 9; nt2++) {
      int col = (sel * 9 + nt2) * 16 + l16;
#pragma unroll
      for (int rr = 0; rr < 4; rr++)
        gsum[mat][quad * 4 + rr][col] = accn[nt2][rr];
    }
  }
  __syncthreads();
  {
    int r = tid >> 4, cb = (tid & 15) * 6;
    int row = n * 64 + q * 16 + r;
#pragma unroll
    for (int k = 0; k < 6; k++) {
      int c = cb + k;
      float v;
      if (t > 0) {
        float xr = gsum[0][r][c] + gnbi[c] + gsum[1][r][c] + gnbh[c];
        float xi = gsum[0][r][96 + c] + gnbi[96 + c] + gsum[1][r][96 + c] + gnbh[96 + c];
        float xn = gsum[0][r][192 + c] + gnbi[192 + c];
        float hn = gsum[1][r][192 + c] + gnbh[192 + c];
        float rg = sigm(xr);
        float ig = sigm(xi);
        float ng = tanh_f(xn + rg * hn);
        v = (1.0f - ig) * ng + ig * hvf[r][c];
      } else {
        v = (c < 32) ? xinf[r][c] : aggf[r][c - 32];
      }
      cnb[r][c] = (bf16)v;
      hnode[row * 96 + c] = v;
    }
  }
  __syncthreads();
  {
    bf16x8 af3[3];
#pragma unroll
    for (int kf = 0; kf < 3; kf++)
      af3[kf] = *(const bf16x8*)&cnb[l16][kf * 32 + quad * 8];
    f32x4 accn = {0.f, 0.f, 0.f, 0.f};
#pragma unroll
    for (int kf = 0; kf < 3; kf++) {
      bf16x8 bfrag = *(const bf16x8*)&OW1[((wv * 3 + kf) * 64 + ln) * 8];
      accn = mfma_bf16(af3[kf], bfrag, accn);
    }
    int col = wv * 16 + l16;
    float bias = ob1[col];
#pragma unroll
    for (int rr = 0; rr < 4; rr++) {
      float vv = accn[rr] + bias;
      s1b[quad * 4 + rr][col] = (bf16)(vv > 0.f ? vv : 0.f);
    }
  }
  __syncthreads();
  {
    bf16x8 af2[2];
#pragma unroll
    for (int kf = 0; kf < 2; kf++)
      af2[kf] = *(const bf16x8*)&s1b[l16][kf * 32 + quad * 8];
    f32x4 accn = {0.f, 0.f, 0.f, 0.f};
#pragma unroll
    for (int kf = 0; kf < 2; kf++) {
      bf16x8 bfrag = *(const bf16x8*)&OW2[((wv * 2 + kf) * 64 + ln) * 8];
      accn = mfma_bf16(af2[kf], bfrag, accn);
    }
    int col = wv * 16 + l16;
    float bias = ob2[col];
#pragma unroll
    for (int rr = 0; rr < 4; rr++) {
      float vv = accn[rr] + bias;
      s2b[quad * 4 + rr][col] = (bf16)(vv > 0.f ? vv : 0.f);
    }
  }
  __syncthreads();
  if (wv < 2) {
    bf16x8 af2[2];
#pragma unroll
    for (int kf = 0; kf < 2; kf++)
      af2[kf] = *(const bf16x8*)&s2b[l16][kf * 32 + quad * 8];
    f32x4 accn = {0.f, 0.f, 0.f, 0.f};
#pragma unroll
    for (int kf = 0; kf < 2; kf++) {
      bf16x8 bfrag = *(const bf16x8*)&OW3[((wv * 2 + kf) * 64 + ln) * 8];
      accn = mfma_bf16(af2[kf], bfrag, accn);
    }
    int d = wv * 16 + l16;
    float bias = ob3[d];
#pragma unroll
    for (int rr = 0; rr < 4; rr++) {
      int r = quad * 4 + rr;
      int b = q * 16 + r;
      float xm = xinf[r][d] + accn[rr] + bias;
      int base = (b * 32 + n) * 32 + d;
      out[524288 + base * 16 + t] = xm;
      out[1572864 + base * 16 + t] = xm;
      if (t >= NSTEP) out[base * 8 + (t - NSTEP)] = xm;
      float vnext = (t + 1 < NSTEP) ? x[base * 8 + (t + 1)] : xm;
      xf[n * 2048 + b * 32 + d] = vnext;
      xb[n * 2048 + b * 32 + d] = (bf16)vnext;
    }
  }
}

extern "C" void kernel_launch(void* const* d_in, const int* in_sizes, int n_in,
                              void* d_out, int out_size, void* d_ws, size_t ws_size,
                              hipStream_t stream) {
  const float* x     = (const float*)d_in[0];
  const float* z     = (const float*)d_in[1];
  const int*   es    = (const int*)d_in[2];
  const float* msgW1 = (const float*)d_in[6];
  const float* msgb1 = (const float*)d_in[7];
  const float* msgW2 = (const float*)d_in[8];
  const float* msgb2 = (const float*)d_in[9];
  const float* oW1   = (const float*)d_in[10];
  const float* ob1   = (const float*)d_in[11];
  const float* oW2   = (const float*)d_in[12];
  const float* ob2   = (const float*)d_in[13];
  const float* oW3   = (const float*)d_in[14];
  const float* ob3   = (const float*)d_in[15];
  const float* geWi  = (const float*)d_in[16];
  const float* gebi  = (const float*)d_in[17];
  const float* geWh  = (const float*)d_in[18];
  const float* gebh  = (const float*)d_in[19];
  const float* gnWi  = (const float*)d_in[20];
  const float* gnbi  = (const float*)d_in[21];
  const float* gnWh  = (const float*)d_in[22];
  const float* gnbh  = (const float*)d_in[23];
  float* out = (float*)d_out;

  char* p = (char*)d_ws;
  bf16*  hed   = (bf16*)p;   p += (size_t)NE * 4096 * 2;   // 8.1 MB
  float* xf    = (float*)p;  p += 65536 * 4;
  bf16*  xb    = (bf16*)p;   p += 65536 * 2;
  float* hnode = (float*)p;  p += 196608 * 4;
  bf16*  B1sw  = (bf16*)p;   p += 12288 * 2;
  bf16*  B2sw  = (bf16*)p;   p += 12288 * 2;
  bf16*  GIsw  = (bf16*)p;   p += 12288 * 2;
  bf16*  GHsw  = (bf16*)p;   p += 12288 * 2;
  bf16*  GNsw  = (bf16*)p;   p += 55296 * 2;
  bf16*  OW1s  = (bf16*)p;   p += 6144 * 2;
  bf16*  OW2s  = (bf16*)p;   p += 4096 * 2;
  bf16*  OW3s  = (bf16*)p;   p += 2048 * 2;

  prep_weights<<<204, 256, 0, stream>>>(msgW1, msgW2, geWi, geWh, gnWi, gnWh,
                                        oW1, oW2, oW3,
                                        B1sw, B2sw, GIsw, GHsw, GNsw,
                                        OW1s, OW2s, OW3s);
  copy_x<<<256, 256, 0, stream>>>(x, xf, xb);

  for (int t = 0; t < NTT; t++) {
    edge_step<<<NE / 2, 512, 0, stream>>>(xb, es, z, B1sw, B2sw, msgb1, msgb2,
                                          GIsw, GHsw, gebi, gebh, hed, t);
    node_kernel<<<128, 256, 0, stream>>>(x, hed, xf, xb, hnode, GNsw, gnbi, gnbh,
                                         OW1s, ob1, OW2s, ob2, OW3s, ob3,
                                         out, t);
  }
}